// Round 12
// baseline (113.400 us; speedup 1.0000x reference)
//
#include <hip/hip_runtime.h>

#define NQ 32768
#define NC 8192
#define CFEAT 128
#define CSPLIT 64
#define TILE (NC / CSPLIT)   // 128 coords per split
#define BLK 256
#define QPT 4                // queries per thread (phase 1): QPT4=98 < QPT8=100 < QPT16=102
#define QPB (BLK * QPT)      // 1024 queries per block
#define GX (NQ / QPB)        // 32 -> phase-1 grid (32, 64) = 2048 blocks

// ws layout: [0, 8 MB) f32 bestd[NQ][CSPLIT] ([q][s]: phase-2 wave reads one
// 256 B row per query — R2-proven); then float4 ctab[NC] (128 KB).
//
// NUMERICS IS FROZEN (R3/R4 lesson): the distance chain MUST be exactly
//   t = mul(cx', px); t = fma(cy', py, t); t = fma(cz', pz, t); d = cc + t
// with ctab entry (-2cx, -2cy, -2cz, ((cx*cx + cy*cy) + cz*cz)).
// Flip-free vs np's argmin (R0/R2/R5/R6/R7/R10/R11: absmax 0.0). The 3-fma
// variant flips near-tie queries (R3/R4: 4.047). pk halves run the exact
// IEEE-RN sequence per coord (R6/R11-proven). Phase 2 consumes the SAME
// stored ctab bits (R1 lesson: never recompute cc across kernels).
//
// STRUCTURE LESSONS (counter-backed):
//  - R10: NO in-loop index tracking (53 us vs ~25; 2.5x) — min-only +
//    wave-level equality rescan.
//  - R6/R11: phase-1 is LDS-PIPE-bound, not VALU-bound (pk packing neutral);
//    QPT ladder 98/100/102 for 4/8/16 shows TLP amortization cancels LDS
//    traffic amortization. R12 therefore moves the wave-uniform ctab
//    broadcast OFF the LDS pipe onto VMEM (1 request/wave, L1/L2-hit;
//    R0-proven pattern): LDS usage -> 0.
//    Visibility: each block WRITES its own split's ctab then __syncthreads
//    (vmcnt drain) before reading; L1 is write-through; concurrent blocks
//    write IDENTICAL bits so any order/stale line is benign; phase 2 is
//    after the kernel boundary.
//  - R5: phase 2 stays wave-per-query, 8192 blocks (max TLP).
//  - R8: no cooperative launch / occupancy queries in kernel_launch.
#define BESTD_OFF 0
#define CTAB_OFF ((size_t)NQ * CSPLIT * 4)

typedef float f32x2 __attribute__((ext_vector_type(2)));

// Phase 1: per-split min DISTANCE only — no index tracking, no LDS.
// Inner loop per 2 coords per query:
//   v_pk_mul + v_pk_fma + v_pk_fma + v_pk_add + v_min3 = 5 insts.
__global__ __launch_bounds__(BLK, 4) void argmin_split(
    const float* __restrict__ coords, const float* __restrict__ points,
    float* __restrict__ bestd, float4* ctab) {
  const int s = blockIdx.y;
  const int base = s * TILE;

  // Every block stages its split's 128 ctab entries to GLOBAL memory
  // (self-contained: its own writes are what it reads back; other writers
  // of the same addresses produce identical bits).
  if (threadIdx.x < TILE) {
    const int i = base + threadIdx.x;
    const float cx = coords[i * 3 + 0];
    const float cy = coords[i * 3 + 1];
    const float cz = coords[i * 3 + 2];
    float xx = cx * cx, yy = cy * cy, zz = cz * cz;
    // Opaque barrier: forbid contracting these products into the adds.
    asm volatile("" : "+v"(xx), "+v"(yy), "+v"(zz));
    const float cc = (xx + yy) + zz;
    ctab[i] = make_float4(-2.0f * cx, -2.0f * cy, -2.0f * cz, cc);
  }

  const int q0 = blockIdx.x * QPB + threadIdx.x;
  float px[QPT], py[QPT], pz[QPT], best[QPT];
  #pragma unroll
  for (int k = 0; k < QPT; ++k) {
    const int q = q0 + k * BLK;
    px[k] = points[q * 3 + 0];
    py[k] = points[q * 3 + 1];
    pz[k] = points[q * 3 + 2];
    best[k] = __builtin_inff();
  }
  __threadfence_block();   // belt-and-braces: stores drained before reads
  __syncthreads();

  const float4* ct = (const float4*)ctab;
  #pragma unroll 4
  for (int p = 0; p < TILE / 2; ++p) {
    // Wave-uniform global reads: 1 VMEM request per wave, L1/L2-hit —
    // zero LDS-pipe traffic (the R11-diagnosed bottleneck).
    const float4 c0 = ct[base + 2 * p];
    const float4 c1 = ct[base + 2 * p + 1];
    const f32x2 X = {c0.x, c1.x}, Y = {c0.y, c1.y};
    const f32x2 Z = {c0.z, c1.z}, W = {c0.w, c1.w};
    #pragma unroll
    for (int k = 0; k < QPT; ++k) {
      f32x2 t = X * (f32x2){px[k], px[k]};                     // pk_mul (RN)
      t = __builtin_elementwise_fma(Y, (f32x2){py[k], py[k]}, t);  // pk_fma
      t = __builtin_elementwise_fma(Z, (f32x2){pz[k], pz[k]}, t);  // pk_fma
      const f32x2 d = W + t;                                   // pk_add (RN)
      best[k] = fminf(fminf(best[k], d.x), d.y);               // v_min3_f32
    }
  }

  #pragma unroll
  for (int k = 0; k < QPT; ++k) {
    const int q = q0 + k * BLK;
    bestd[(size_t)q * CSPLIT + s] = best[k];
  }
}

// Phase 2 (R2-proven, verbatim): one wave per query — reduce 64 split-mins
// (shfl min + ballot/ffs -> lowest winning split); equality-rescan that
// split's 128 coords from the SHARED global ctab (same bits + same frozen
// scalar chain as the pk halves -> hit guaranteed; first match = lowest
// coord). Tiebreak == np.argmin's global first-index. Gather feature row,
// 64 lanes x float2.
__global__ __launch_bounds__(256) void rescan_gather(
    const float4* __restrict__ ctab, const float* __restrict__ points,
    const float* __restrict__ bestd, const float* __restrict__ feature,
    float2* __restrict__ out) {
  const int q = blockIdx.x * 4 + (threadIdx.x >> 6);
  const int l = threadIdx.x & 63;

  // lane l holds split l's min — 256 B coalesced read per wave
  const float v = bestd[(size_t)q * CSPLIT + l];
  float m = v;
  #pragma unroll
  for (int off = 32; off; off >>= 1) m = fminf(m, __shfl_xor(m, off, 64));
  const unsigned long long bs = __ballot(v == m);
  const int sstar = __ffsll(bs) - 1;            // lowest split attaining min

  const float qx = points[q * 3 + 0];           // wave-uniform
  const float qy = points[q * 3 + 1];
  const float qz = points[q * 3 + 2];
  const int b2 = sstar * TILE;

  const float4 c0 = ctab[b2 + l];               // coalesced, lanes consecutive
  const float4 c1 = ctab[b2 + 64 + l];
  float t0 = __fmul_rn(c0.x, qx);                      // FROZEN CHAIN (R2)
  t0 = __fmaf_rn(c0.y, qy, t0);
  t0 = __fmaf_rn(c0.z, qz, t0);
  const float d0 = __fadd_rn(c0.w, t0);
  float t1 = __fmul_rn(c1.x, qx);
  t1 = __fmaf_rn(c1.y, qy, t1);
  t1 = __fmaf_rn(c1.z, qz, t1);
  const float d1 = __fadd_rn(c1.w, t1);

  const unsigned long long b0 = __ballot(d0 == m);
  const unsigned long long b1 = __ballot(d1 == m);
  int off_in;
  if (b0 | b1) {
    off_in = b0 ? (__ffsll(b0) - 1) : (64 + __ffsll(b1) - 1);
  } else {
    // Defense in depth (should be unreachable): true argmin over the 128
    // rescanned candidates, first-index tiebreak.
    float dm = fminf(d0, d1);
    int im = (d0 <= d1) ? l : (64 + l);
    #pragma unroll
    for (int off = 32; off; off >>= 1) {
      const float od = __shfl_xor(dm, off, 64);
      const int oi = __shfl_xor(im, off, 64);
      if (od < dm || (od == dm && oi < im)) { dm = od; im = oi; }
    }
    off_in = im;
  }
  const int idx = b2 + off_in;

  const float2* fr = (const float2*)(feature + (size_t)idx * CFEAT);
  out[(size_t)q * (CFEAT / 2) + l] = fr[l];
}

extern "C" void kernel_launch(void* const* d_in, const int* in_sizes, int n_in,
                              void* d_out, int out_size, void* d_ws, size_t ws_size,
                              hipStream_t stream) {
  const float* coords  = (const float*)d_in[0];   // [8192, 3]
  const float* feature = (const float*)d_in[1];   // [8192, 128]
  const float* points  = (const float*)d_in[2];   // [32768, 3]
  float2* out = (float2*)d_out;                   // [32768, 128]

  float* bestd = (float*)((char*)d_ws + BESTD_OFF);
  float4* ctab = (float4*)((char*)d_ws + CTAB_OFF);

  dim3 grid1(GX, CSPLIT);                         // (32, 64) = 2048 blocks
  argmin_split<<<grid1, BLK, 0, stream>>>(coords, points, bestd, ctab);

  rescan_gather<<<NQ / 4, 256, 0, stream>>>(ctab, points, bestd, feature,
                                            (float2*)out);
}